// Round 11
// baseline (685.843 us; speedup 1.0000x reference)
//
#include <hip/hip_runtime.h>
#include <hip/hip_bf16.h>

typedef __bf16 bf16;
typedef bf16 bf16x4 __attribute__((ext_vector_type(4)));
typedef bf16 bf16x8 __attribute__((ext_vector_type(8)));
typedef float f32x4 __attribute__((ext_vector_type(4)));

#define MFMA16(a, b, c) __builtin_amdgcn_mfma_f32_16x16x32_bf16((a), (b), (c), 0, 0, 0)

constexpr float kScale = 0.17677669529663687f;  // 1/sqrt(32)

// ---- workspace offsets (bytes) ----
constexpr int WQKV_OFF = 0;         // bf16[768*256]
constexpr int WPROJ_OFF = 393216;   // bf16[256*256]
constexpr int BIAS_OFF = 524288;    // f32[8][49 m][49 n]  (transposed bias)
constexpr int BQKV_OFF = 601120;    // f32[768]
constexpr size_t QKG_OFF = 604672;  // bf16 QK^T chunk buffer: cw * 25600 elems

constexpr int QS = 410;   // LDS chunk stride (elems); dword-stride 205 (odd) => debanked
constexpr int GQS = 400;  // global QK^T chunk stride (elems), compact

__global__ void prep_kernel(const float* __restrict__ w_qkv, const float* __restrict__ b_qkv,
                            const float* __restrict__ w_proj, const float* __restrict__ bias_table,
                            const int* __restrict__ rel_index, char* __restrict__ ws) {
  int i = blockIdx.x * 256 + threadIdx.x;
  bf16* wqkvb = (bf16*)(ws + WQKV_OFF);
  bf16* wprojb = (bf16*)(ws + WPROJ_OFF);
  float* biasx = (float*)(ws + BIAS_OFF);
  float* bqs = (float*)(ws + BQKV_OFF);
  if (i < 196608) {
    float v = w_qkv[i];
    if (i < 65536) v *= kScale;  // q rows (o<256): fold scale
    wqkvb[i] = (bf16)v;
  } else if (i < 262144) {
    int j = i - 196608;
    wprojb[j] = (bf16)w_proj[j];
  } else if (i < 281352) {
    int j = i - 262144;  // 8*2401, layout [h][m][n]
    int h = j / 2401, nm = j - h * 2401;
    int mm = nm / 49, nn = nm - mm * 49;
    biasx[j] = bias_table[rel_index[nn * 49 + mm] * 8 + h];  // bias[h][nn][mm]
  } else if (i < 282120) {
    int j = i - 281352;
    bqs[j] = b_qkv[j] * (j < 256 ? kScale : 1.0f);
  }
}

// Shuffle-transpose: treats (lo,hi) as a 32-row pair; f[j] = Pair[row32=g*8+j][col=c].
__device__ __forceinline__ bf16x8 xpose8(f32x4 lo, f32x4 hi, int base, bool glow) {
  bf16x8 f;
#pragma unroll
  for (int i = 0; i < 4; ++i) {
    float a0 = __shfl(lo[i], base);
    float a1 = __shfl(lo[i], base + 16);
    float b0 = __shfl(hi[i], base);
    float b1 = __shfl(hi[i], base + 16);
    f[i] = (bf16)(glow ? a0 : b0);
    f[i + 4] = (bf16)(glow ? a1 : b1);
  }
  return f;
}

__device__ __forceinline__ void stage_x(const float* __restrict__ xw, bf16* xb, int tid) {
#pragma unroll
  for (int it = 0; it < 13; ++it) {
    int idx = it * 256 + tid;
    if (idx < 3136) {
      int n = idx >> 6, c4 = (idx & 63) << 2;
      float4 v = ((const float4*)xw)[idx];
      bf16x4 b4;
      b4[0] = (bf16)v.x; b4[1] = (bf16)v.y; b4[2] = (bf16)v.z; b4[3] = (bf16)v.w;
      *(bf16x4*)(xb + ((c4 >> 3) * QS + n * 8 + (c4 & 7))) = b4;
    }
  }
}

// ============ kernel A: Q,K GEMM -> global QK^T (chunk-local) ============
__global__ __launch_bounds__(256, 4) void qk_kernel(
    const float* __restrict__ x, const char* __restrict__ ws, bf16* __restrict__ qkg, int w0) {
  __shared__ bf16 xb[32 * QS + 128];
  const bf16* wqkvb = (const bf16*)(ws + WQKV_OFF);
  const float* bqs = (const float*)(ws + BQKV_OFF);

  const int tid = threadIdx.x;
  const int lane = tid & 63;
  const int wave = tid >> 6;
  const int g = lane >> 4;
  const int c = lane & 15;

  stage_x(x + (size_t)(w0 + blockIdx.x) * 12544, xb, tid);
  __syncthreads();

  bf16* qw = qkg + (size_t)blockIdx.x * 25600;

  for (int qd = 0; qd < 2; ++qd) {
    const int ot0 = wave * 8 + qd * 4;
    f32x4 acc[4][4] = {};  // [tile][nt]
#pragma unroll
    for (int ks = 0; ks < 8; ++ks) {
      bf16x8 b[4];
#pragma unroll
      for (int nt = 0; nt < 4; ++nt)
        b[nt] = *(const bf16x8*)(xb + (ks * 4 + g) * QS + c * 8 + nt * 128);
      bf16x8 a[4];
#pragma unroll
      for (int t = 0; t < 4; ++t)
        a[t] = *(const bf16x8*)(wqkvb + ((ot0 + t) * 16 + c) * 256 + ks * 32 + g * 8);
#pragma unroll
      for (int t = 0; t < 4; ++t)
#pragma unroll
        for (int nt = 0; nt < 4; ++nt) acc[t][nt] = MFMA16(a[t], b[nt], acc[t][nt]);
    }
#pragma unroll
    for (int t = 0; t < 4; ++t) {
      const int ot = ot0 + t;
      const int ob = ot * 16 + g * 4;
      const float bq0 = bqs[ob], bq1 = bqs[ob + 1], bq2 = bqs[ob + 2], bq3 = bqs[ob + 3];
      const int oc = ob >> 3, olow = ob & 7;
#pragma unroll
      for (int nt = 0; nt < 4; ++nt) {
        int n = nt * 16 + c;
        if (n < 50) {
          bool ok = (n < 49);
          bf16x4 pk;
          pk[0] = ok ? (bf16)(acc[t][nt][0] + bq0) : (bf16)0.f;
          pk[1] = ok ? (bf16)(acc[t][nt][1] + bq1) : (bf16)0.f;
          pk[2] = ok ? (bf16)(acc[t][nt][2] + bq2) : (bf16)0.f;
          pk[3] = ok ? (bf16)(acc[t][nt][3] + bq3) : (bf16)0.f;
          *(bf16x4*)(qw + (oc * GQS + n * 8 + olow)) = pk;
        }
      }
    }
  }
}

// ============ kernel B: V-GEMM + attention + proj ============
__global__ __launch_bounds__(256, 3) void attn2_kernel(
    const float* __restrict__ x, const float* __restrict__ mask, const float* __restrict__ b_proj,
    const char* __restrict__ ws, const bf16* __restrict__ qkg, float* __restrict__ out, int w0) {
  __shared__ char smem[26240 + 25088 + 128];
  bf16* xb = (bf16*)smem;                 // x staging; later attn-out (ao)
  float* outf = (float*)(smem + 26240);   // proj f32 half staging

  const bf16* wqkvb = (const bf16*)(ws + WQKV_OFF);
  const bf16* wprojb = (const bf16*)(ws + WPROJ_OFF);
  const float* biasx = (const float*)(ws + BIAS_OFF);
  const float* bqs = (const float*)(ws + BQKV_OFF);

  const int tid = threadIdx.x;
  const int w = w0 + blockIdx.x;
  const int lane = tid & 63;
  const int wave = tid >> 6;
  const int g = lane >> 4;
  const int c = lane & 15;

  stage_x(x + (size_t)w * 12544, xb, tid);
  __syncthreads();

  const int base = (g & 1) * 32 + c;
  const bool glow = (g < 2);

  // ---- V-GEMM quad (D[n][o], A=X shared, B=W per tile) -> va registers ----
  bf16x8 va[2][2][2];  // [hh][dt][ks]
  {
    f32x4 acc[4][4] = {};  // [tile][mt]
#pragma unroll
    for (int ks = 0; ks < 8; ++ks) {
      bf16x8 a[4];
#pragma unroll
      for (int mt = 0; mt < 4; ++mt)
        a[mt] = *(const bf16x8*)(xb + (ks * 4 + g) * QS + c * 8 + mt * 128);
      bf16x8 bw[4];
#pragma unroll
      for (int t = 0; t < 4; ++t)
        bw[t] = *(const bf16x8*)(wqkvb + (512 + (wave * 4 + t) * 16 + c) * 256 + ks * 32 + g * 8);
#pragma unroll
      for (int t = 0; t < 4; ++t)
#pragma unroll
        for (int mt = 0; mt < 4; ++mt) acc[t][mt] = MFMA16(a[mt], bw[t], acc[t][mt]);
    }
#pragma unroll
    for (int t = 0; t < 4; ++t) {
      const int o = 512 + (wave * 4 + t) * 16 + c;
      const float bv = bqs[o];
#pragma unroll
      for (int mt = 0; mt < 4; ++mt) {
        acc[t][mt][0] += bv; acc[t][mt][1] += bv; acc[t][mt][2] += bv; acc[t][mt][3] += bv;
      }
#pragma unroll
      for (int ks = 0; ks < 2; ++ks) {
        bf16x8 f = xpose8(acc[t][2 * ks], acc[t][2 * ks + 1], base, glow);
#pragma unroll
        for (int j = 0; j < 8; ++j) {
          int m = ks * 32 + g * 8 + j;
          if (m >= 49) f[j] = (bf16)0.f;
        }
        va[t >> 1][t & 1][ks] = f;
      }
    }
  }
  __syncthreads();  // all xb reads done -> ao may overlay region A
  bf16* ao = xb;

  // ---- attention: wave -> heads 2w, 2w+1; qa/kb loaded from global QK^T ----
  const float* mk = mask + (size_t)w * 2401;
  const bf16* qw = qkg + (size_t)blockIdx.x * 25600;

#pragma unroll
  for (int hh = 0; hh < 2; ++hh) {
    const int h = wave * 2 + hh;
    const float* bhT = biasx + h * 2401;

    bf16x8 qa[4], kb[4];
#pragma unroll
    for (int rt = 0; rt < 4; ++rt) {
      int n = rt * 16 + c; n = n > 49 ? 49 : n;  // row 49 = zeros
      qa[rt] = *(const bf16x8*)(qw + (h * 4 + g) * GQS + n * 8);
    }
#pragma unroll
    for (int mt = 0; mt < 4; ++mt) {
      int m = mt * 16 + c; m = m > 49 ? 49 : m;
      kb[mt] = *(const bf16x8*)(qw + ((32 + h * 4 + g) * GQS + m * 8));
    }

    // S^T[m][n] all 16 MFMAs
    f32x4 s[4][4] = {};  // [mt][nt]
#pragma unroll
    for (int mt = 0; mt < 4; ++mt)
#pragma unroll
      for (int nt = 0; nt < 4; ++nt) s[mt][nt] = MFMA16(kb[mt], qa[nt], s[mt][nt]);

    float bi[16], mi[16];
#define GATHER(NT)                                              \
    {                                                           \
      const int n_ = (NT) * 16 + c;                             \
      const int nc_ = n_ > 48 ? 48 : n_;                        \
      _Pragma("unroll") for (int mt = 0; mt < 4; ++mt)          \
        _Pragma("unroll") for (int i = 0; i < 4; ++i) {         \
          int m_ = mt * 16 + g * 4 + i;                         \
          int mc_ = m_ > 48 ? 48 : m_;                          \
          bi[mt * 4 + i] = bhT[mc_ * 49 + nc_];                 \
          mi[mt * 4 + i] = mk[nc_ * 49 + mc_];                  \
        }                                                       \
    }

    GATHER(0);
    f32x4 oacc[2][4] = {};
#pragma unroll
    for (int nt = 0; nt < 4; ++nt) {
      const int n = nt * 16 + c;
      const bool nok = (n < 49);
      float p[4][4];
      float sum = 0.f;
#pragma unroll
      for (int mt = 0; mt < 4; ++mt)
#pragma unroll
        for (int i = 0; i < 4; ++i) {
          int m = mt * 16 + g * 4 + i;
          float v = s[mt][nt][i] + bi[mt * 4 + i] + mi[mt * 4 + i];
          float pv = (nok && m < 49) ? __expf(v) : 0.f;
          p[mt][i] = pv;
          sum += pv;
        }
      sum += __shfl_xor(sum, 16);
      sum += __shfl_xor(sum, 32);
      float rinv = nok ? (1.0f / sum) : 0.0f;
#pragma unroll
      for (int mt = 0; mt < 4; ++mt)
#pragma unroll
        for (int i = 0; i < 4; ++i) p[mt][i] *= rinv;

      if (nt < 3) {  // prefetch next column-tile's bias/mask
        if (nt == 0) GATHER(1);
        if (nt == 1) GATHER(2);
        if (nt == 2) GATHER(3);
      }

#pragma unroll
      for (int ks = 0; ks < 2; ++ks) {
        bf16x8 f;
#pragma unroll
        for (int j = 0; j < 8; ++j) {
          int src = ((g & 1) * 2 + (j >> 2)) * 16 + c;
          float vA = __shfl(p[2 * ks][j & 3], src);
          float vB = __shfl(p[2 * ks + 1][j & 3], src);
          f[j] = (bf16)(glow ? vA : vB);
        }
#pragma unroll
        for (int dt = 0; dt < 2; ++dt) oacc[dt][nt] = MFMA16(va[hh][dt][ks], f, oacc[dt][nt]);
      }
    }
#undef GATHER

    // attn-out -> ao (wave-private chunks)
#pragma unroll
    for (int dt = 0; dt < 2; ++dt) {
      int cb = h * 32 + dt * 16 + g * 4;
      int cc = cb >> 3, clow = cb & 7;
#pragma unroll
      for (int nt = 0; nt < 4; ++nt) {
        int n = nt * 16 + c;
        if (n < 49) {
          bf16x4 pk;
          pk[0] = (bf16)oacc[dt][nt][0]; pk[1] = (bf16)oacc[dt][nt][1];
          pk[2] = (bf16)oacc[dt][nt][2]; pk[3] = (bf16)oacc[dt][nt][3];
          *(bf16x4*)(ao + (cc * QS + n * 8 + clow)) = pk;
        }
      }
    }
  }
  __syncthreads();  // ao complete

  // ---- proj in two co-halves (pairs, ks-outermost), staged via outf ----
  float4* outw4 = (float4*)(out + (size_t)w * 12544);
  const float4* outf4 = (const float4*)outf;
#pragma unroll 1
  for (int half = 0; half < 2; ++half) {
    f32x4 acc[2][4] = {};  // [tt][mt]
#pragma unroll
    for (int ks = 0; ks < 8; ++ks) {
      bf16x8 a[4];
#pragma unroll
      for (int mt = 0; mt < 4; ++mt)
        a[mt] = *(const bf16x8*)(ao + (ks * 4 + g) * QS + c * 8 + mt * 128);
      bf16x8 bw[2];
#pragma unroll
      for (int tt = 0; tt < 2; ++tt)
        bw[tt] = *(const bf16x8*)(wprojb +
                                  ((half * 8 + wave * 2 + tt) * 16 + c) * 256 + ks * 32 + g * 8);
#pragma unroll
      for (int tt = 0; tt < 2; ++tt)
#pragma unroll
        for (int mt = 0; mt < 4; ++mt) acc[tt][mt] = MFMA16(a[mt], bw[tt], acc[tt][mt]);
    }
#pragma unroll
    for (int tt = 0; tt < 2; ++tt) {
      const int ctl = wave * 2 + tt;
      const int ct = half * 8 + ctl;
      const float bp = b_proj[ct * 16 + c];
      const int q = ctl * 4 + (c >> 2);
      const int c3 = c & 3;
#pragma unroll
      for (int mt = 0; mt < 4; ++mt) {
#pragma unroll
        for (int i = 0; i < 4; ++i) {
          int n = mt * 16 + g * 4 + i;
          if (n < 49) outf[n * 128 + ((q ^ (n & 7)) << 2) + c3] = acc[tt][mt][i] + bp;
        }
      }
    }
    __syncthreads();
#pragma unroll
    for (int it = 0; it < 7; ++it) {
      int f = it * 256 + tid;
      if (f < 1568) {
        int n = f >> 5, q2 = f & 31;
        outw4[n * 64 + half * 32 + q2] = outf4[n * 32 + (q2 ^ (n & 7))];
      }
    }
    __syncthreads();
  }
}

// ============ fused fallback (R9, 444 us) if ws too small for QK buffer ============
__global__ __launch_bounds__(256, 2) void fused_kernel(
    const float* __restrict__ x, const float* __restrict__ mask, const float* __restrict__ b_proj,
    const char* __restrict__ ws, float* __restrict__ out) {
  extern __shared__ char dsm[];
  bf16* xb = (bf16*)(dsm);
  bf16* qk = (bf16*)(dsm + 26240);
  float* outf = (float*)(dsm + 26240);

  const bf16* wqkvb = (const bf16*)(ws + WQKV_OFF);
  const bf16* wprojb = (const bf16*)(ws + WPROJ_OFF);
  const float* biasx = (const float*)(ws + BIAS_OFF);
  const float* bqs = (const float*)(ws + BQKV_OFF);

  const int tid = threadIdx.x;
  const int w = blockIdx.x;
  const int lane = tid & 63;
  const int wave = tid >> 6;
  const int g = lane >> 4;
  const int c = lane & 15;

  stage_x(x + (size_t)w * 12544, xb, tid);
  __syncthreads();

  for (int qd = 0; qd < 2; ++qd) {
    const int ot0 = wave * 8 + qd * 4;
    f32x4 acc[4][4] = {};
#pragma unroll
    for (int ks = 0; ks < 8; ++ks) {
      bf16x8 b[4];
#pragma unroll
      for (int nt = 0; nt < 4; ++nt)
        b[nt] = *(const bf16x8*)(xb + (ks * 4 + g) * QS + c * 8 + nt * 128);
      bf16x8 a[4];
#pragma unroll
      for (int t = 0; t < 4; ++t)
        a[t] = *(const bf16x8*)(wqkvb + ((ot0 + t) * 16 + c) * 256 + ks * 32 + g * 8);
#pragma unroll
      for (int t = 0; t < 4; ++t)
#pragma unroll
        for (int nt = 0; nt < 4; ++nt) acc[t][nt] = MFMA16(a[t], b[nt], acc[t][nt]);
    }
#pragma unroll
    for (int t = 0; t < 4; ++t) {
      const int ot = ot0 + t;
      const int ob = ot * 16 + g * 4;
      const float bq0 = bqs[ob], bq1 = bqs[ob + 1], bq2 = bqs[ob + 2], bq3 = bqs[ob + 3];
      const int oc = ob >> 3, olow = ob & 7;
#pragma unroll
      for (int nt = 0; nt < 4; ++nt) {
        int n = nt * 16 + c;
        if (n < 50) {
          bool ok = (n < 49);
          bf16x4 pk;
          pk[0] = ok ? (bf16)(acc[t][nt][0] + bq0) : (bf16)0.f;
          pk[1] = ok ? (bf16)(acc[t][nt][1] + bq1) : (bf16)0.f;
          pk[2] = ok ? (bf16)(acc[t][nt][2] + bq2) : (bf16)0.f;
          pk[3] = ok ? (bf16)(acc[t][nt][3] + bq3) : (bf16)0.f;
          *(bf16x4*)(qk + (oc * QS + n * 8 + olow)) = pk;
        }
      }
    }
  }

  const int base = (g & 1) * 32 + c;
  const bool glow = (g < 2);

  bf16x8 va[2][2][2];
  {
    f32x4 acc[4][4] = {};
#pragma unroll
    for (int ks = 0; ks < 8; ++ks) {
      bf16x8 a[4];
#pragma unroll
      for (int mt = 0; mt < 4; ++mt)
        a[mt] = *(const bf16x8*)(xb + (ks * 4 + g) * QS + c * 8 + mt * 128);
      bf16x8 bw[4];
#pragma unroll
      for (int t = 0; t < 4; ++t)
        bw[t] = *(const bf16x8*)(wqkvb + (512 + (wave * 4 + t) * 16 + c) * 256 + ks * 32 + g * 8);
#pragma unroll
      for (int t = 0; t < 4; ++t)
#pragma unroll
        for (int mt = 0; mt < 4; ++mt) acc[t][mt] = MFMA16(a[mt], bw[t], acc[t][mt]);
    }
#pragma unroll
    for (int t = 0; t < 4; ++t) {
      const int o = 512 + (wave * 4 + t) * 16 + c;
      const float bv = bqs[o];
#pragma unroll
      for (int mt = 0; mt < 4; ++mt) {
        acc[t][mt][0] += bv; acc[t][mt][1] += bv; acc[t][mt][2] += bv; acc[t][mt][3] += bv;
      }
#pragma unroll
      for (int ks = 0; ks < 2; ++ks) {
        bf16x8 f = xpose8(acc[t][2 * ks], acc[t][2 * ks + 1], base, glow);
#pragma unroll
        for (int j = 0; j < 8; ++j) {
          int m = ks * 32 + g * 8 + j;
          if (m >= 49) f[j] = (bf16)0.f;
        }
        va[t >> 1][t & 1][ks] = f;
      }
    }
  }
  __syncthreads();

  const float* mk = mask + (size_t)w * 2401;

#pragma unroll
  for (int hh = 0; hh < 2; ++hh) {
    const int h = wave * 2 + hh;
    const float* bhT = biasx + h * 2401;

    bf16x8 qa[4], kb[4];
#pragma unroll
    for (int rt = 0; rt < 4; ++rt) {
      int n = rt * 16 + c; n = n > 49 ? 49 : n;
      qa[rt] = *(const bf16x8*)(qk + ((h * 4 + g) * QS + n * 8));
    }
#pragma unroll
    for (int mt = 0; mt < 4; ++mt) {
      int m = mt * 16 + c; m = m > 49 ? 49 : m;
      kb[mt] = *(const bf16x8*)(qk + ((32 + h * 4 + g) * QS + m * 8));
    }

    f32x4 s[4][4] = {};
#pragma unroll
    for (int mt = 0; mt < 4; ++mt)
#pragma unroll
      for (int nt = 0; nt < 4; ++nt) s[mt][nt] = MFMA16(kb[mt], qa[nt], s[mt][nt]);

    float bi[16], mi[16];
#define GATHER(NT)                                              \
    {                                                           \
      const int n_ = (NT) * 16 + c;                             \
      const int nc_ = n_ > 48 ? 48 : n_;                        \
      _Pragma("unroll") for (int mt = 0; mt < 4; ++mt)          \
        _Pragma("unroll") for (int i = 0; i < 4; ++i) {         \
          int m_ = mt * 16 + g * 4 + i;                         \
          int mc_ = m_ > 48 ? 48 : m_;                          \
          bi[mt * 4 + i] = bhT[mc_ * 49 + nc_];                 \
          mi[mt * 4 + i] = mk[nc_ * 49 + mc_];                  \
        }                                                       \
    }

    GATHER(0);
    f32x4 oacc[2][4] = {};
#pragma unroll
    for (int nt = 0; nt < 4; ++nt) {
      const int n = nt * 16 + c;
      const bool nok = (n < 49);
      float p[4][4];
      float sum = 0.f;
#pragma unroll
      for (int mt = 0; mt < 4; ++mt)
#pragma unroll
        for (int i = 0; i < 4; ++i) {
          int m = mt * 16 + g * 4 + i;
          float v = s[mt][nt][i] + bi[mt * 4 + i] + mi[mt * 4 + i];
          float pv = (nok && m < 49) ? __expf(v) : 0.f;
          p[mt][i] = pv;
          sum += pv;
        }
      sum += __shfl_xor(sum, 16);
      sum += __shfl_xor(sum, 32);
      float rinv = nok ? (1.0f / sum) : 0.0f;
#pragma unroll
      for (int mt = 0; mt < 4; ++mt)
#pragma unroll
        for (int i = 0; i < 4; ++i) p[mt][i] *= rinv;

      if (nt < 3) {
        if (nt == 0) GATHER(1);
        if (nt == 1) GATHER(2);
        if (nt == 2) GATHER(3);
      }

#pragma unroll
      for (int ks = 0; ks < 2; ++ks) {
        bf16x8 f;
#pragma unroll
        for (int j = 0; j < 8; ++j) {
          int src = ((g & 1) * 2 + (j >> 2)) * 16 + c;
          float vA = __shfl(p[2 * ks][j & 3], src);
          float vB = __shfl(p[2 * ks + 1][j & 3], src);
          f[j] = (bf16)(glow ? vA : vB);
        }
#pragma unroll
        for (int dt = 0; dt < 2; ++dt) oacc[dt][nt] = MFMA16(va[hh][dt][ks], f, oacc[dt][nt]);
      }
    }
#undef GATHER

#pragma unroll
    for (int dt = 0; dt < 2; ++dt) {
      int cb = h * 32 + dt * 16 + g * 4;
      int cc = cb >> 3, clow = cb & 7;
#pragma unroll
      for (int nt = 0; nt < 4; ++nt) {
        int n = nt * 16 + c;
        if (n < 49) {
          bf16x4 pk;
          pk[0] = (bf16)oacc[dt][nt][0]; pk[1] = (bf16)oacc[dt][nt][1];
          pk[2] = (bf16)oacc[dt][nt][2]; pk[3] = (bf16)oacc[dt][nt][3];
          *(bf16x4*)(xb + (cc * QS + n * 8 + clow)) = pk;
        }
      }
    }
  }
  __syncthreads();

  {
    f32x4 acc[4][4] = {};
#pragma unroll
    for (int ks = 0; ks < 8; ++ks) {
      bf16x8 a[4];
#pragma unroll
      for (int mt = 0; mt < 4; ++mt)
        a[mt] = *(const bf16x8*)(xb + (ks * 4 + g) * QS + c * 8 + mt * 128);
      bf16x8 bw[4];
#pragma unroll
      for (int t = 0; t < 4; ++t)
        bw[t] = *(const bf16x8*)(wprojb + ((wave * 4 + t) * 16 + c) * 256 + ks * 32 + g * 8);
#pragma unroll
      for (int t = 0; t < 4; ++t)
#pragma unroll
        for (int mt = 0; mt < 4; ++mt) acc[t][mt] = MFMA16(a[mt], bw[t], acc[t][mt]);
    }
#pragma unroll
    for (int t = 0; t < 4; ++t) {
      const int ct = wave * 4 + t;
      const float bp = b_proj[ct * 16 + c];
      const int co = ct * 16 + c, q = co >> 2, c3 = co & 3;
#pragma unroll
      for (int mt = 0; mt < 4; ++mt) {
#pragma unroll
        for (int i = 0; i < 4; ++i) {
          int n = mt * 16 + g * 4 + i;
          if (n < 49) outf[n * 256 + ((q ^ (n & 15)) << 2) + c3] = acc[t][mt][i] + bp;
        }
      }
    }
  }
  __syncthreads();

  float4* outw4 = (float4*)(out + (size_t)w * 12544);
  const float4* outf4 = (const float4*)outf;
#pragma unroll
  for (int it = 0; it < 13; ++it) {
    int f = it * 256 + tid;
    if (f < 3136) {
      int n = f >> 6, q = f & 63;
      outw4[f] = outf4[n * 64 + (q ^ (n & 15))];
    }
  }
}

extern "C" void kernel_launch(void* const* d_in, const int* in_sizes, int n_in,
                              void* d_out, int out_size, void* d_ws, size_t ws_size,
                              hipStream_t stream) {
  const float* x = (const float*)d_in[0];
  const float* mask = (const float*)d_in[1];
  const float* w_qkv = (const float*)d_in[2];
  const float* b_qkv = (const float*)d_in[3];
  const float* w_proj = (const float*)d_in[4];
  const float* b_proj = (const float*)d_in[5];
  const float* bias_table = (const float*)d_in[6];
  const int* rel_index = (const int*)d_in[7];
  float* out = (float*)d_out;
  char* ws = (char*)d_ws;

  (void)in_sizes; (void)n_in; (void)out_size;

  prep_kernel<<<1103, 256, 0, stream>>>(w_qkv, b_qkv, w_proj, bias_table, rel_index, ws);

  size_t avail = ws_size > QKG_OFF ? ws_size - QKG_OFF : 0;
  long cwl = (long)(avail / 51200);  // bytes per window of QK^T
  int cw = cwl > 1024 ? 1024 : (int)cwl;

  if (cw >= 512) {
    bf16* qkg = (bf16*)(ws + QKG_OFF);
    for (int s = 0; s < 4096; s += cw) {
      int nb = (4096 - s) < cw ? (4096 - s) : cw;
      qk_kernel<<<nb, 256, 0, stream>>>(x, ws, qkg, s);
      attn2_kernel<<<nb, 256, 0, stream>>>(x, mask, b_proj, ws, qkg, out, s);
    }
  } else {
    hipFuncSetAttribute((const void*)fused_kernel, hipFuncAttributeMaxDynamicSharedMemorySize,
                        78720);
    fused_kernel<<<4096, 256, 78720, stream>>>(x, mask, b_proj, ws, out);
  }
}

// Round 13
// 482.381 us; speedup vs baseline: 1.4218x; 1.4218x over previous
//
#include <hip/hip_runtime.h>
#include <hip/hip_bf16.h>

typedef __bf16 bf16;
typedef bf16 bf16x4 __attribute__((ext_vector_type(4)));
typedef bf16 bf16x8 __attribute__((ext_vector_type(8)));
typedef float f32x4 __attribute__((ext_vector_type(4)));

#define MFMA16(a, b, c) __builtin_amdgcn_mfma_f32_16x16x32_bf16((a), (b), (c), 0, 0, 0)

constexpr float kScale = 0.17677669529663687f;  // 1/sqrt(32)

// ---- workspace offsets (bytes) ----
constexpr int WQKV_OFF = 0;          // bf16[768*256]
constexpr int WPROJ_OFF = 393216;    // bf16[256*256]
constexpr int BIASR_OFF = 524288;    // f32[8][4 nt][4 mt][4 i][64 lane] = 131072 B
constexpr int BQKV_OFF = 655360;     // f32[768]
constexpr size_t MASKR_OFF = 658432; // bf16[4096][4][4][4][64] = 33554432 B (ws >= 53MB proven)

constexpr int QS = 410;  // LDS chunk stride (elems); dword-stride 205 (odd) => debanked
constexpr int LDS_BYTES = 78720;

__global__ void prep_kernel(const float* __restrict__ w_qkv, const float* __restrict__ b_qkv,
                            const float* __restrict__ w_proj, const float* __restrict__ bias_table,
                            const int* __restrict__ rel_index, char* __restrict__ ws) {
  int i = blockIdx.x * 256 + threadIdx.x;
  bf16* wqkvb = (bf16*)(ws + WQKV_OFF);
  bf16* wprojb = (bf16*)(ws + WPROJ_OFF);
  float* biasr = (float*)(ws + BIASR_OFF);
  float* bqs = (float*)(ws + BQKV_OFF);
  if (i < 196608) {
    float v = w_qkv[i];
    if (i < 65536) v *= kScale;  // q rows (o<256): fold scale
    wqkvb[i] = (bf16)v;
  } else if (i < 262144) {
    int j = i - 196608;
    wprojb[j] = (bf16)w_proj[j];
  } else if (i < 294912) {
    int j = i - 262144;  // [h][nt][mt][i2][lane], 8*4096 elements
    int h = j >> 12, r = j & 4095;
    int lane = r & 63, q = r >> 6;  // q in [0,64)
    int i2 = q & 3, p = q >> 2, mt = p & 3, nt = p >> 2;
    int nn = nt * 16 + (lane & 15); nn = nn > 48 ? 48 : nn;
    int mm = mt * 16 + (lane >> 4) * 4 + i2; mm = mm > 48 ? 48 : mm;
    biasr[j] = bias_table[rel_index[nn * 49 + mm] * 8 + h];
  } else if (i < 295680) {
    int j = i - 294912;
    bqs[j] = b_qkv[j] * (j < 256 ? kScale : 1.0f);
  }
}

// Rearrange mask[w][n][m] -> maskr[w][nt][mt][i][lane] (bf16), clamps baked in.
__global__ void maskr_kernel(const float* __restrict__ mask, char* __restrict__ ws) {
  const int w = blockIdx.x;
  const float* mk = mask + (size_t)w * 2401;
  bf16* mr = (bf16*)(ws + MASKR_OFF) + (size_t)w * 4096;
#pragma unroll
  for (int rep = 0; rep < 4; ++rep) {
    int o = (rep * 256 + threadIdx.x) * 4;  // [0,4096) step 4
    int q = o >> 6;  // (nt*4+mt)*4+i2, [0,64)
    int i2 = q & 3, p = q >> 2, mt = p & 3, nt = p >> 2;
    bf16x4 v;
#pragma unroll
    for (int j = 0; j < 4; ++j) {
      int L = (o & 63) + j;
      int nn = nt * 16 + (L & 15); nn = nn > 48 ? 48 : nn;
      int mm = mt * 16 + (L >> 4) * 4 + i2; mm = mm > 48 ? 48 : mm;
      v[j] = (bf16)mk[nn * 49 + mm];
    }
    *(bf16x4*)(mr + o) = v;
  }
}

// Shuffle-transpose: treats (lo,hi) as a 32-row pair; f[j] = Pair[row32=g*8+j][col=c].
__device__ __forceinline__ bf16x8 xpose8(f32x4 lo, f32x4 hi, int base, bool glow) {
  bf16x8 f;
#pragma unroll
  for (int i = 0; i < 4; ++i) {
    float a0 = __shfl(lo[i], base);
    float a1 = __shfl(lo[i], base + 16);
    float b0 = __shfl(hi[i], base);
    float b1 = __shfl(hi[i], base + 16);
    f[i] = (bf16)(glow ? a0 : b0);
    f[i + 4] = (bf16)(glow ? a1 : b1);
  }
  return f;
}

__global__ __launch_bounds__(256, 2) void attn_kernel(
    const float* __restrict__ x, const float* __restrict__ b_proj,
    const char* __restrict__ ws, float* __restrict__ out) {
  extern __shared__ char smem[];
  bf16* xb = (bf16*)(smem);
  bf16* qk = (bf16*)(smem + 26240);
  float* outf = (float*)(smem + 26240);  // overlays qk after attention

  const bf16* wqkvb = (const bf16*)(ws + WQKV_OFF);
  const bf16* wprojb = (const bf16*)(ws + WPROJ_OFF);
  const float* biasr = (const float*)(ws + BIASR_OFF);
  const float* bqs = (const float*)(ws + BQKV_OFF);

  const int tid = threadIdx.x;
  const int w = blockIdx.x;
  const int lane = tid & 63;
  const int wave = tid >> 6;  // 0..3
  const int g = lane >> 4;    // 16-lane group
  const int c = lane & 15;

  const float* xw = x + (size_t)w * 12544;

  // ---- stage x -> xb bf16, [cc][n<49][8] ----
#pragma unroll
  for (int it = 0; it < 13; ++it) {
    int idx = it * 256 + tid;
    if (idx < 3136) {
      int n = idx >> 6, c4 = (idx & 63) << 2;
      float4 v = ((const float4*)xw)[idx];
      bf16x4 b4;
      b4[0] = (bf16)v.x; b4[1] = (bf16)v.y; b4[2] = (bf16)v.z; b4[3] = (bf16)v.w;
      *(bf16x4*)(xb + ((c4 >> 3) * QS + n * 8 + (c4 & 7))) = b4;
    }
  }
  __syncthreads();

  // ---- GEMM1 (Q,K -> qk LDS): 2 quads of 4 o-tiles; k-step outermost ----
  for (int qd = 0; qd < 2; ++qd) {
    const int ot0 = wave * 8 + qd * 4;
    f32x4 acc[4][4] = {};  // [tile][nt]
#pragma unroll
    for (int ks = 0; ks < 8; ++ks) {
      bf16x8 b[4];
#pragma unroll
      for (int nt = 0; nt < 4; ++nt)
        b[nt] = *(const bf16x8*)(xb + (ks * 4 + g) * QS + c * 8 + nt * 128);
      bf16x8 a[4];
#pragma unroll
      for (int t = 0; t < 4; ++t)
        a[t] = *(const bf16x8*)(wqkvb + ((ot0 + t) * 16 + c) * 256 + ks * 32 + g * 8);
#pragma unroll
      for (int t = 0; t < 4; ++t)
#pragma unroll
        for (int nt = 0; nt < 4; ++nt) acc[t][nt] = MFMA16(a[t], b[nt], acc[t][nt]);
    }
#pragma unroll
    for (int t = 0; t < 4; ++t) {
      const int ot = ot0 + t;
      const int ob = ot * 16 + g * 4;
      const float bq0 = bqs[ob], bq1 = bqs[ob + 1], bq2 = bqs[ob + 2], bq3 = bqs[ob + 3];
      const int oc = ob >> 3, olow = ob & 7;
#pragma unroll
      for (int nt = 0; nt < 4; ++nt) {
        int n = nt * 16 + c;
        if (n < 50) {
          bool ok = (n < 49);
          bf16x4 pk;
          pk[0] = ok ? (bf16)(acc[t][nt][0] + bq0) : (bf16)0.f;
          pk[1] = ok ? (bf16)(acc[t][nt][1] + bq1) : (bf16)0.f;
          pk[2] = ok ? (bf16)(acc[t][nt][2] + bq2) : (bf16)0.f;
          pk[3] = ok ? (bf16)(acc[t][nt][3] + bq3) : (bf16)0.f;
          *(bf16x4*)(qk + (oc * QS + n * 8 + olow)) = pk;
        }
      }
    }
  }

  const int base = (g & 1) * 32 + c;
  const bool glow = (g < 2);

  // ---- V-GEMM quad (D[n][o], A=X shared, B=W per tile) -> va registers ----
  bf16x8 va[2][2][2];  // [hh][dt][ks]
  {
    f32x4 acc[4][4] = {};  // [tile][mt]
#pragma unroll
    for (int ks = 0; ks < 8; ++ks) {
      bf16x8 a[4];
#pragma unroll
      for (int mt = 0; mt < 4; ++mt)
        a[mt] = *(const bf16x8*)(xb + (ks * 4 + g) * QS + c * 8 + mt * 128);
      bf16x8 bw[4];
#pragma unroll
      for (int t = 0; t < 4; ++t)
        bw[t] = *(const bf16x8*)(wqkvb + (512 + (wave * 4 + t) * 16 + c) * 256 + ks * 32 + g * 8);
#pragma unroll
      for (int t = 0; t < 4; ++t)
#pragma unroll
        for (int mt = 0; mt < 4; ++mt) acc[t][mt] = MFMA16(a[mt], bw[t], acc[t][mt]);
    }
#pragma unroll
    for (int t = 0; t < 4; ++t) {
      const int o = 512 + (wave * 4 + t) * 16 + c;
      const float bv = bqs[o];
#pragma unroll
      for (int mt = 0; mt < 4; ++mt) {
        acc[t][mt][0] += bv; acc[t][mt][1] += bv; acc[t][mt][2] += bv; acc[t][mt][3] += bv;
      }
#pragma unroll
      for (int ks = 0; ks < 2; ++ks) {
        bf16x8 f = xpose8(acc[t][2 * ks], acc[t][2 * ks + 1], base, glow);
#pragma unroll
        for (int j = 0; j < 8; ++j) {
          int m = ks * 32 + g * 8 + j;
          if (m >= 49) f[j] = (bf16)0.f;
        }
        va[t >> 1][t & 1][ks] = f;
      }
    }
  }
  __syncthreads();  // all xb reads done; qk fully written

  // ---- attention (S^T): wave -> heads 2w, 2w+1; fragment-ordered gathers ----
  const bf16* mkR = (const bf16*)(ws + MASKR_OFF) + (size_t)w * 4096;

#pragma unroll
  for (int hh = 0; hh < 2; ++hh) {
    const int h = wave * 2 + hh;
    const float* bhR = biasr + h * 4096;  // [nt][mt][i][lane] f32

    bf16x8 qa[4], kb[4];
#pragma unroll
    for (int rt = 0; rt < 4; ++rt) {
      int n = rt * 16 + c; n = n > 49 ? 49 : n;  // row 49 = zeros
      qa[rt] = *(const bf16x8*)(qk + ((h * 4 + g) * QS + n * 8));
    }
#pragma unroll
    for (int mt = 0; mt < 4; ++mt) {
      int m = mt * 16 + c; m = m > 49 ? 49 : m;
      kb[mt] = *(const bf16x8*)(qk + ((32 + h * 4 + g) * QS + m * 8));
    }

    // S^T[m][n] all 16 MFMAs
    f32x4 s[4][4] = {};  // [mt][nt]
#pragma unroll
    for (int mt = 0; mt < 4; ++mt)
#pragma unroll
      for (int nt = 0; nt < 4; ++nt) s[mt][nt] = MFMA16(kb[mt], qa[nt], s[mt][nt]);

    float bi[16], mi[16];
#define GATHER(NT)                                                        \
    {                                                                     \
      _Pragma("unroll") for (int mt = 0; mt < 4; ++mt)                    \
        _Pragma("unroll") for (int i = 0; i < 4; ++i) {                   \
          int off = (((NT) * 4 + mt) * 4 + i) * 64 + lane;                \
          bi[mt * 4 + i] = bhR[off];                                      \
          mi[mt * 4 + i] = (float)mkR[off];                               \
        }                                                                 \
    }

    GATHER(0);
    f32x4 oacc[2][4] = {};
#pragma unroll
    for (int nt = 0; nt < 4; ++nt) {
      const int n = nt * 16 + c;
      const bool nok = (n < 49);
      float p[4][4];
      float sum = 0.f;
#pragma unroll
      for (int mt = 0; mt < 4; ++mt)
#pragma unroll
        for (int i = 0; i < 4; ++i) {
          int m = mt * 16 + g * 4 + i;
          float v = s[mt][nt][i] + bi[mt * 4 + i] + mi[mt * 4 + i];
          float pv = (nok && m < 49) ? __expf(v) : 0.f;
          p[mt][i] = pv;
          sum += pv;
        }
      sum += __shfl_xor(sum, 16);
      sum += __shfl_xor(sum, 32);
      float rinv = nok ? (1.0f / sum) : 0.0f;
#pragma unroll
      for (int mt = 0; mt < 4; ++mt)
#pragma unroll
        for (int i = 0; i < 4; ++i) p[mt][i] *= rinv;

      if (nt < 3) {  // prefetch next column-tile's bias/mask under shuffles+PV
        if (nt == 0) GATHER(1);
        if (nt == 1) GATHER(2);
        if (nt == 2) GATHER(3);
      }

      // P^T fragments via register shuffle, then PV
#pragma unroll
      for (int ks = 0; ks < 2; ++ks) {
        bf16x8 f;
#pragma unroll
        for (int j = 0; j < 8; ++j) {
          int src = ((g & 1) * 2 + (j >> 2)) * 16 + c;
          float vA = __shfl(p[2 * ks][j & 3], src);
          float vB = __shfl(p[2 * ks + 1][j & 3], src);
          f[j] = (bf16)(glow ? vA : vB);
        }
#pragma unroll
        for (int dt = 0; dt < 2; ++dt) oacc[dt][nt] = MFMA16(va[hh][dt][ks], f, oacc[dt][nt]);
      }
    }
#undef GATHER

    // attn-out -> xb rows n<49
#pragma unroll
    for (int dt = 0; dt < 2; ++dt) {
      int cb = h * 32 + dt * 16 + g * 4;
      int cc = cb >> 3, clow = cb & 7;
#pragma unroll
      for (int nt = 0; nt < 4; ++nt) {
        int n = nt * 16 + c;
        if (n < 49) {
          bf16x4 pk;
          pk[0] = (bf16)oacc[dt][nt][0]; pk[1] = (bf16)oacc[dt][nt][1];
          pk[2] = (bf16)oacc[dt][nt][2]; pk[3] = (bf16)oacc[dt][nt][3];
          *(bf16x4*)(xb + (cc * QS + n * 8 + clow)) = pk;
        }
      }
    }
  }
  __syncthreads();  // attn-out complete; qk dead -> outf overlay safe

  // ---- proj quad (A=attn-out in xb, B=Wp per tile) -> outf (swizzled) ----
  {
    f32x4 acc[4][4] = {};  // [tile][mt]
#pragma unroll
    for (int ks = 0; ks < 8; ++ks) {
      bf16x8 a[4];
#pragma unroll
      for (int mt = 0; mt < 4; ++mt)
        a[mt] = *(const bf16x8*)(xb + (ks * 4 + g) * QS + c * 8 + mt * 128);
      bf16x8 bw[4];
#pragma unroll
      for (int t = 0; t < 4; ++t)
        bw[t] = *(const bf16x8*)(wprojb + ((wave * 4 + t) * 16 + c) * 256 + ks * 32 + g * 8);
#pragma unroll
      for (int t = 0; t < 4; ++t)
#pragma unroll
        for (int mt = 0; mt < 4; ++mt) acc[t][mt] = MFMA16(a[mt], bw[t], acc[t][mt]);
    }
#pragma unroll
    for (int t = 0; t < 4; ++t) {
      const int ct = wave * 4 + t;
      const float bp = b_proj[ct * 16 + c];
      const int co = ct * 16 + c, q = co >> 2, c3 = co & 3;
#pragma unroll
      for (int mt = 0; mt < 4; ++mt) {
#pragma unroll
        for (int i = 0; i < 4; ++i) {
          int n = mt * 16 + g * 4 + i;
          if (n < 49) outf[n * 256 + ((q ^ (n & 15)) << 2) + c3] = acc[t][mt][i] + bp;
        }
      }
    }
  }
  __syncthreads();

  // ---- coalesced copy LDS -> global (full float4 lines) ----
  float4* outw4 = (float4*)(out + (size_t)w * 12544);
  const float4* outf4 = (const float4*)outf;
#pragma unroll
  for (int it = 0; it < 13; ++it) {
    int f = it * 256 + tid;
    if (f < 3136) {
      int n = f >> 6, q = f & 63;
      outw4[f] = outf4[n * 64 + (q ^ (n & 15))];
    }
  }
}

extern "C" void kernel_launch(void* const* d_in, const int* in_sizes, int n_in,
                              void* d_out, int out_size, void* d_ws, size_t ws_size,
                              hipStream_t stream) {
  const float* x = (const float*)d_in[0];
  const float* mask = (const float*)d_in[1];
  const float* w_qkv = (const float*)d_in[2];
  const float* b_qkv = (const float*)d_in[3];
  const float* w_proj = (const float*)d_in[4];
  const float* b_proj = (const float*)d_in[5];
  const float* bias_table = (const float*)d_in[6];
  const int* rel_index = (const int*)d_in[7];
  float* out = (float*)d_out;
  char* ws = (char*)d_ws;

  (void)in_sizes; (void)n_in; (void)out_size; (void)ws_size;

  hipFuncSetAttribute((const void*)attn_kernel, hipFuncAttributeMaxDynamicSharedMemorySize,
                      LDS_BYTES);

  prep_kernel<<<1155, 256, 0, stream>>>(w_qkv, b_qkv, w_proj, bias_table, rel_index, ws);
  maskr_kernel<<<4096, 256, 0, stream>>>(mask, ws);
  attn_kernel<<<4096, 256, LDS_BYTES, stream>>>(x, b_proj, ws, out);
}